// Round 5
// baseline (350.639 us; speedup 1.0000x reference)
//
#include <hip/hip_runtime.h>
#include <hip/hip_bf16.h>

#define D 64

// ---- CSR build ------------------------------------------------------------
// Harness delivers integer inputs as int32 (edge_index -> const int*).

__global__ void count_k(const int* __restrict__ dst, int* __restrict__ cnt, int E) {
    int e0 = (blockIdx.x * blockDim.x + threadIdx.x) * 4;
    if (e0 + 4 <= E) {
        int4 d = *(const int4*)(dst + e0);
        atomicAdd(&cnt[d.x], 1); atomicAdd(&cnt[d.y], 1);
        atomicAdd(&cnt[d.z], 1); atomicAdd(&cnt[d.w], 1);
    } else {
        for (int e = e0; e < E; ++e) atomicAdd(&cnt[dst[e]], 1);
    }
}

__global__ void scanA_k(const int* __restrict__ cnt, int* __restrict__ rowptr,
                        int* __restrict__ bsum, int N) {
    __shared__ int tmp[256];
    int gid = blockIdx.x * 256 + threadIdx.x;
    int v = (gid < N) ? cnt[gid] : 0;
    tmp[threadIdx.x] = v;
    __syncthreads();
    for (int off = 1; off < 256; off <<= 1) {
        int t = (threadIdx.x >= off) ? tmp[threadIdx.x - off] : 0;
        __syncthreads();
        tmp[threadIdx.x] += t;
        __syncthreads();
    }
    if (gid < N) rowptr[gid] = tmp[threadIdx.x] - v;   // exclusive within block
    if (threadIdx.x == 255) bsum[blockIdx.x] = tmp[255];
}

__global__ void scanB_k(int* __restrict__ bsum, int nb) {  // nb <= 256
    __shared__ int tmp[256];
    int v = (threadIdx.x < nb) ? bsum[threadIdx.x] : 0;
    tmp[threadIdx.x] = v;
    __syncthreads();
    for (int off = 1; off < 256; off <<= 1) {
        int t = (threadIdx.x >= off) ? tmp[threadIdx.x - off] : 0;
        __syncthreads();
        tmp[threadIdx.x] += t;
        __syncthreads();
    }
    if (threadIdx.x < nb) bsum[threadIdx.x] = tmp[threadIdx.x] - v;  // exclusive
}

__global__ void scanC_k(int* __restrict__ rowptr, int* __restrict__ cursor,
                        const int* __restrict__ bsum, int N, int E) {
    int gid = blockIdx.x * 256 + threadIdx.x;
    if (gid < N) {
        int v = rowptr[gid] + bsum[blockIdx.x];
        rowptr[gid] = v;
        cursor[gid] = v;
    }
    if (blockIdx.x == 0 && threadIdx.x == 0) rowptr[N] = E;
}

__global__ void fill_k(const int* __restrict__ src, const int* __restrict__ dst,
                       int* __restrict__ cursor, int* __restrict__ col, int E) {
    int e0 = (blockIdx.x * blockDim.x + threadIdx.x) * 4;
    if (e0 + 4 <= E) {
        int4 d = *(const int4*)(dst + e0);
        int4 s = *(const int4*)(src + e0);
        col[atomicAdd(&cursor[d.x], 1)] = s.x;
        col[atomicAdd(&cursor[d.y], 1)] = s.y;
        col[atomicAdd(&cursor[d.z], 1)] = s.z;
        col[atomicAdd(&cursor[d.w], 1)] = s.w;
    } else {
        for (int e = e0; e < E; ++e)
            col[atomicAdd(&cursor[dst[e]], 1)] = src[e];
    }
}

// ---- aggregation: wave-per-node mean gather, no LDS, 8 outstanding loads ----

__global__ __launch_bounds__(256) void agg_k(
    const float* __restrict__ xin, const int* __restrict__ rowptr,
    const int* __restrict__ col, float* __restrict__ agg, int N)
{
    const int lane = threadIdx.x & 63;
    const int n = blockIdx.x * (blockDim.x >> 6) + (threadIdx.x >> 6);
    if (n >= N) return;
    const int beg = rowptr[n], end = rowptr[n + 1];
    float a0 = 0.f, a1 = 0.f, a2 = 0.f, a3 = 0.f;
    float a4 = 0.f, a5 = 0.f, a6 = 0.f, a7 = 0.f;
    int j = beg;
    for (; j + 8 <= end; j += 8) {                 // 8 coalesced 256B gathers in flight
        int c0 = col[j + 0], c1 = col[j + 1], c2 = col[j + 2], c3 = col[j + 3];
        int c4 = col[j + 4], c5 = col[j + 5], c6 = col[j + 6], c7 = col[j + 7];
        a0 += xin[(size_t)c0 * D + lane];
        a1 += xin[(size_t)c1 * D + lane];
        a2 += xin[(size_t)c2 * D + lane];
        a3 += xin[(size_t)c3 * D + lane];
        a4 += xin[(size_t)c4 * D + lane];
        a5 += xin[(size_t)c5 * D + lane];
        a6 += xin[(size_t)c6 * D + lane];
        a7 += xin[(size_t)c7 * D + lane];
    }
    for (; j < end; ++j) a0 += xin[(size_t)col[j] * D + lane];
    float s = ((a0 + a1) + (a2 + a3)) + ((a4 + a5) + (a6 + a7));
    s *= 1.0f / fmaxf((float)(end - beg), 1.0f);   // mean with deg>=1 guard
    agg[(size_t)n * D + lane] = s;
}

// ---- MLP v3: register-blocked, W via wave-uniform scalar loads --------------
// Wave w of a block owns f-slice [16w,16w+16); thread owns 2 nodes x 16 f
// (acc=32 VGPRs, 32 independent FMA chains). W/bias indices are wave-uniform
// -> s_load_dwordx4 from K$ (SMEM pipe; SGPR srcs are free in v_fma).
// No LDS at all. One barrier before stores (layer 2: out aliases agg).

__device__ __forceinline__ float tanh_fast(float v) {
    float e = __expf(2.f * v);                     // inf-safe at extremes
    return 1.f - 2.f * __builtin_amdgcn_rcpf(e + 1.f);
}

template <bool TANH>
__global__ __launch_bounds__(256) void mlp_k(
    const float* __restrict__ agg, const float* __restrict__ xin,
    const float* __restrict__ Wl, const float* __restrict__ Wr,
    const float* __restrict__ bias, float* __restrict__ out, int N)
{
    const int lane = threadIdx.x & 63;
    const int f0   = (threadIdx.x >> 6) << 4;      // wave -> f block
    const int n0   = (blockIdx.x << 7) + lane;     // 128 nodes per block
    const int n1   = n0 + 64;
    const bool v0 = n0 < N, v1 = n1 < N;

    const float4* __restrict__ W4l = (const float4*)Wl;
    const float4* __restrict__ W4r = (const float4*)Wr;
    const float4* __restrict__ A4  = (const float4*)agg;
    const float4* __restrict__ X4  = (const float4*)xin;
    const float4 z4 = make_float4(0.f, 0.f, 0.f, 0.f);

    float acc0[16], acc1[16];
    #pragma unroll
    for (int i = 0; i < 16; ++i) {
        float b = bias[f0 + i];                    // uniform -> s_load
        acc0[i] = b; acc1[i] = b;
    }

    for (int kc = 0; kc < 16; ++kc) {              // pass 1: Wl * agg
        float4 a0 = v0 ? A4[(size_t)n0 * 16 + kc] : z4;
        float4 a1 = v1 ? A4[(size_t)n1 * 16 + kc] : z4;
        #pragma unroll
        for (int i = 0; i < 16; ++i) {
            float4 w = W4l[((f0 + i) << 4) + kc];  // uniform -> s_load_dwordx4
            acc0[i] = fmaf(a0.w, w.w, fmaf(a0.z, w.z, fmaf(a0.y, w.y, fmaf(a0.x, w.x, acc0[i]))));
            acc1[i] = fmaf(a1.w, w.w, fmaf(a1.z, w.z, fmaf(a1.y, w.y, fmaf(a1.x, w.x, acc1[i]))));
        }
    }
    for (int kc = 0; kc < 16; ++kc) {              // pass 2: Wr * x
        float4 a0 = v0 ? X4[(size_t)n0 * 16 + kc] : z4;
        float4 a1 = v1 ? X4[(size_t)n1 * 16 + kc] : z4;
        #pragma unroll
        for (int i = 0; i < 16; ++i) {
            float4 w = W4r[((f0 + i) << 4) + kc];
            acc0[i] = fmaf(a0.w, w.w, fmaf(a0.z, w.z, fmaf(a0.y, w.y, fmaf(a0.x, w.x, acc0[i]))));
            acc1[i] = fmaf(a1.w, w.w, fmaf(a1.z, w.z, fmaf(a1.y, w.y, fmaf(a1.x, w.x, acc1[i]))));
        }
    }

    if (TANH) {
        #pragma unroll
        for (int i = 0; i < 16; ++i) { acc0[i] = tanh_fast(acc0[i]); acc1[i] = tanh_fast(acc1[i]); }
    }

    __syncthreads();   // layer 2: out aliases agg; all reads done before stores

    float4* O4 = (float4*)out;
    const int fq = f0 >> 2;
    if (v0) {
        #pragma unroll
        for (int q = 0; q < 4; ++q)
            O4[(size_t)n0 * 16 + fq + q] =
                make_float4(acc0[4*q], acc0[4*q+1], acc0[4*q+2], acc0[4*q+3]);
    }
    if (v1) {
        #pragma unroll
        for (int q = 0; q < 4; ++q)
            O4[(size_t)n1 * 16 + fq + q] =
                make_float4(acc1[4*q], acc1[4*q+1], acc1[4*q+2], acc1[4*q+3]);
    }
}

// ---- launcher ---------------------------------------------------------------

extern "C" void kernel_launch(void* const* d_in, const int* in_sizes, int n_in,
                              void* d_out, int out_size, void* d_ws, size_t ws_size,
                              hipStream_t stream) {
    const float* x   = (const float*)d_in[0];
    const int*   ei  = (const int*)d_in[1];     // int64 in ref -> int32 here
    const float* Wl1 = (const float*)d_in[2];
    const float* bl1 = (const float*)d_in[3];
    const float* Wr1 = (const float*)d_in[4];
    const float* Wl2 = (const float*)d_in[5];
    const float* bl2 = (const float*)d_in[6];
    const float* Wr2 = (const float*)d_in[7];

    const int N = in_sizes[0] / D;
    const int E = in_sizes[1] / 2;
    const int* srcI = ei;        // edge_index[0]
    const int* dstI = ei + E;    // edge_index[1]

    auto al = [](size_t v) { return (v + 255) & ~(size_t)255; };
    char* w = (char*)d_ws;
    size_t off = 0;
    int*   cnt    = (int*)(w + off);  off += al((size_t)N * 4);
    int*   rowptr = (int*)(w + off);  off += al((size_t)(N + 1) * 4);
    int*   cursor = (int*)(w + off);  off += al((size_t)N * 4);
    int*   bsum   = (int*)(w + off);  off += al(1024);
    int*   colA   = (int*)(w + off);  off += al((size_t)E * 4);
    float* h      = (float*)(w + off);  // [N, D] fp32 layer-1 output

    float* aggbuf = (float*)d_out;    // agg scratch; mlp_k block reads all its
                                      // rows before stores (barrier) -> safe
    float* out = (float*)d_out;

    const int NB = (N + 255) / 256;          // 196 <= 256, scanB handles it
    const int EB4 = (E / 4 + 255) / 256;     // int4 edge kernels
    const int AB = (N + 3) / 4;              // agg_k: 4 waves/block, 1 node/wave
    const int MB = (N + 127) / 128;          // mlp_k: 128 nodes/block

    hipMemsetAsync(cnt, 0, (size_t)N * 4, stream);
    count_k<<<EB4, 256, 0, stream>>>(dstI, cnt, E);
    scanA_k<<<NB, 256, 0, stream>>>(cnt, rowptr, bsum, N);
    scanB_k<<<1, 256, 0, stream>>>(bsum, NB);
    scanC_k<<<NB, 256, 0, stream>>>(rowptr, cursor, bsum, N, E);
    fill_k<<<EB4, 256, 0, stream>>>(srcI, dstI, cursor, colA, E);

    // layer 1
    agg_k<<<AB, 256, 0, stream>>>(x, rowptr, colA, aggbuf, N);
    mlp_k<true ><<<MB, 256, 0, stream>>>(aggbuf, x, Wl1, Wr1, bl1, h, N);
    // layer 2
    agg_k<<<AB, 256, 0, stream>>>(h, rowptr, colA, aggbuf, N);
    mlp_k<false><<<MB, 256, 0, stream>>>(aggbuf, h, Wl2, Wr2, bl2, out, N);
}

// Round 6
// 291.463 us; speedup vs baseline: 1.2030x; 1.2030x over previous
//
#include <hip/hip_runtime.h>
#include <hip/hip_bf16.h>

#define D 64

// ---- CSR build ------------------------------------------------------------
// Harness delivers integer inputs as int32 (edge_index -> const int*).

__global__ void count_k(const int* __restrict__ dst, int* __restrict__ cnt, int E) {
    int e0 = (blockIdx.x * blockDim.x + threadIdx.x) * 4;
    if (e0 + 4 <= E) {
        int4 d = *(const int4*)(dst + e0);
        atomicAdd(&cnt[d.x], 1); atomicAdd(&cnt[d.y], 1);
        atomicAdd(&cnt[d.z], 1); atomicAdd(&cnt[d.w], 1);
    } else {
        for (int e = e0; e < E; ++e) atomicAdd(&cnt[dst[e]], 1);
    }
}

__global__ void scanA_k(const int* __restrict__ cnt, int* __restrict__ rowptr,
                        int* __restrict__ bsum, int N) {
    __shared__ int tmp[256];
    int gid = blockIdx.x * 256 + threadIdx.x;
    int v = (gid < N) ? cnt[gid] : 0;
    tmp[threadIdx.x] = v;
    __syncthreads();
    for (int off = 1; off < 256; off <<= 1) {
        int t = (threadIdx.x >= off) ? tmp[threadIdx.x - off] : 0;
        __syncthreads();
        tmp[threadIdx.x] += t;
        __syncthreads();
    }
    if (gid < N) rowptr[gid] = tmp[threadIdx.x] - v;   // exclusive within block
    if (threadIdx.x == 255) bsum[blockIdx.x] = tmp[255];
}

__global__ void scanB_k(int* __restrict__ bsum, int nb) {  // nb <= 256
    __shared__ int tmp[256];
    int v = (threadIdx.x < nb) ? bsum[threadIdx.x] : 0;
    tmp[threadIdx.x] = v;
    __syncthreads();
    for (int off = 1; off < 256; off <<= 1) {
        int t = (threadIdx.x >= off) ? tmp[threadIdx.x - off] : 0;
        __syncthreads();
        tmp[threadIdx.x] += t;
        __syncthreads();
    }
    if (threadIdx.x < nb) bsum[threadIdx.x] = tmp[threadIdx.x] - v;  // exclusive
}

__global__ void scanC_k(int* __restrict__ rowptr, int* __restrict__ cursor,
                        const int* __restrict__ bsum, int N, int E) {
    int gid = blockIdx.x * 256 + threadIdx.x;
    if (gid < N) {
        int v = rowptr[gid] + bsum[blockIdx.x];
        rowptr[gid] = v;
        cursor[gid] = v;
    }
    if (blockIdx.x == 0 && threadIdx.x == 0) rowptr[N] = E;
}

__global__ void fill_k(const int* __restrict__ src, const int* __restrict__ dst,
                       int* __restrict__ cursor, int* __restrict__ col, int E) {
    int e0 = (blockIdx.x * blockDim.x + threadIdx.x) * 4;
    if (e0 + 4 <= E) {
        int4 d = *(const int4*)(dst + e0);
        int4 s = *(const int4*)(src + e0);
        col[atomicAdd(&cursor[d.x], 1)] = s.x;
        col[atomicAdd(&cursor[d.y], 1)] = s.y;
        col[atomicAdd(&cursor[d.z], 1)] = s.z;
        col[atomicAdd(&cursor[d.w], 1)] = s.w;
    } else {
        for (int e = e0; e < E; ++e)
            col[atomicAdd(&cursor[dst[e]], 1)] = src[e];
    }
}

// ---- aggregation: wave-per-node mean gather, no LDS, 8 outstanding loads ----

__global__ __launch_bounds__(256) void agg_k(
    const float* __restrict__ xin, const int* __restrict__ rowptr,
    const int* __restrict__ col, float* __restrict__ agg, int N)
{
    const int lane = threadIdx.x & 63;
    const int n = blockIdx.x * (blockDim.x >> 6) + (threadIdx.x >> 6);
    if (n >= N) return;
    const int beg = rowptr[n], end = rowptr[n + 1];
    float a0 = 0.f, a1 = 0.f, a2 = 0.f, a3 = 0.f;
    float a4 = 0.f, a5 = 0.f, a6 = 0.f, a7 = 0.f;
    int j = beg;
    for (; j + 8 <= end; j += 8) {                 // 8 coalesced 256B gathers in flight
        int c0 = col[j + 0], c1 = col[j + 1], c2 = col[j + 2], c3 = col[j + 3];
        int c4 = col[j + 4], c5 = col[j + 5], c6 = col[j + 6], c7 = col[j + 7];
        a0 += xin[(size_t)c0 * D + lane];
        a1 += xin[(size_t)c1 * D + lane];
        a2 += xin[(size_t)c2 * D + lane];
        a3 += xin[(size_t)c3 * D + lane];
        a4 += xin[(size_t)c4 * D + lane];
        a5 += xin[(size_t)c5 * D + lane];
        a6 += xin[(size_t)c6 * D + lane];
        a7 += xin[(size_t)c7 * D + lane];
    }
    for (; j < end; ++j) a0 += xin[(size_t)col[j] * D + lane];
    float s = ((a0 + a1) + (a2 + a3)) + ((a4 + a5) + (a6 + a7));
    s *= 1.0f / fmaxf((float)(end - beg), 1.0f);   // mean with deg>=1 guard
    agg[(size_t)n * D + lane] = s;
}

// ---- MLP v4: lane=node, wave=64 nodes x 16 features, W via s_load ----------
// f0 is wave-uniform; forced into an SGPR with readfirstlane so the compiler
// emits s_load_dwordx4 for W/bias (K$, scalar pipe, SGPR srcs free in v_fma).
// acc[16]/thread = 16 independent FMA chains. No LDS. Input row (256B/lane)
// is L1-resident across the 16-kc loop.

__device__ __forceinline__ float tanh_fast(float v) {
    float e = __expf(2.f * v);                     // inf-safe at extremes
    return 1.f - 2.f * __builtin_amdgcn_rcpf(e + 1.f);
}

template <bool TANH>
__global__ __launch_bounds__(256) void mlp_k(
    const float* __restrict__ agg, const float* __restrict__ xin,
    const float* __restrict__ Wl, const float* __restrict__ Wr,
    const float* __restrict__ bias, float* __restrict__ out, int N)
{
    const int lane = threadIdx.x & 63;
    const int f0 = __builtin_amdgcn_readfirstlane((threadIdx.x >> 6) << 4); // SGPR
    const int n  = (blockIdx.x << 6) + lane;       // 64 nodes per block
    const bool valid = n < N;

    const float4* __restrict__ W4l = (const float4*)Wl;  // W[f][k]: W4[f*16+kc]
    const float4* __restrict__ W4r = (const float4*)Wr;
    const float4 z4 = make_float4(0.f, 0.f, 0.f, 0.f);

    float acc[16];
    #pragma unroll
    for (int i = 0; i < 16; ++i) acc[i] = bias[f0 + i];   // uniform -> s_load

    const float4* av = (const float4*)agg + (size_t)n * 16;
    for (int kc = 0; kc < 16; ++kc) {              // pass 1: Wl * agg
        float4 a = valid ? av[kc] : z4;
        #pragma unroll
        for (int i = 0; i < 16; ++i) {
            float4 w = W4l[(size_t)(f0 + i) * 16 + kc];   // uniform -> s_load_dwordx4
            acc[i] = fmaf(a.w, w.w, fmaf(a.z, w.z, fmaf(a.y, w.y, fmaf(a.x, w.x, acc[i]))));
        }
    }
    const float4* xv = (const float4*)xin + (size_t)n * 16;
    for (int kc = 0; kc < 16; ++kc) {              // pass 2: Wr * x
        float4 a = valid ? xv[kc] : z4;
        #pragma unroll
        for (int i = 0; i < 16; ++i) {
            float4 w = W4r[(size_t)(f0 + i) * 16 + kc];
            acc[i] = fmaf(a.w, w.w, fmaf(a.z, w.z, fmaf(a.y, w.y, fmaf(a.x, w.x, acc[i]))));
        }
    }

    if (TANH) {
        #pragma unroll
        for (int i = 0; i < 16; ++i) acc[i] = tanh_fast(acc[i]);
    }

    __syncthreads();   // out aliases agg (layer 2): all pass-1 reads of this
                       // block's rows complete before any wave stores them.
                       // (Cross-block: each block reads/writes only its own rows.)

    if (valid) {
        float4* ov = (float4*)out + (size_t)n * 16 + (f0 >> 2);
        #pragma unroll
        for (int q = 0; q < 4; ++q)
            ov[q] = make_float4(acc[4*q], acc[4*q+1], acc[4*q+2], acc[4*q+3]);
    }
}

// ---- launcher ---------------------------------------------------------------

extern "C" void kernel_launch(void* const* d_in, const int* in_sizes, int n_in,
                              void* d_out, int out_size, void* d_ws, size_t ws_size,
                              hipStream_t stream) {
    const float* x   = (const float*)d_in[0];
    const int*   ei  = (const int*)d_in[1];     // int64 in ref -> int32 here
    const float* Wl1 = (const float*)d_in[2];
    const float* bl1 = (const float*)d_in[3];
    const float* Wr1 = (const float*)d_in[4];
    const float* Wl2 = (const float*)d_in[5];
    const float* bl2 = (const float*)d_in[6];
    const float* Wr2 = (const float*)d_in[7];

    const int N = in_sizes[0] / D;
    const int E = in_sizes[1] / 2;
    const int* srcI = ei;        // edge_index[0]
    const int* dstI = ei + E;    // edge_index[1]

    auto al = [](size_t v) { return (v + 255) & ~(size_t)255; };
    char* w = (char*)d_ws;
    size_t off = 0;
    int*   cnt    = (int*)(w + off);  off += al((size_t)N * 4);
    int*   rowptr = (int*)(w + off);  off += al((size_t)(N + 1) * 4);
    int*   cursor = (int*)(w + off);  off += al((size_t)N * 4);
    int*   bsum   = (int*)(w + off);  off += al(1024);
    int*   colA   = (int*)(w + off);  off += al((size_t)E * 4);
    float* h      = (float*)(w + off);  // [N, D] fp32 layer-1 output

    float* aggbuf = (float*)d_out;    // agg scratch; mlp_k block reads all its
                                      // rows before stores (barrier) -> safe
    float* out = (float*)d_out;

    const int NB = (N + 255) / 256;          // 196 <= 256, scanB handles it
    const int EB4 = (E / 4 + 255) / 256;     // int4 edge kernels
    const int AB = (N + 3) / 4;              // agg_k: 4 waves/block, 1 node/wave
    const int MB = (N + 63) / 64;            // mlp_k: 64 nodes/block, 4 waves

    hipMemsetAsync(cnt, 0, (size_t)N * 4, stream);
    count_k<<<EB4, 256, 0, stream>>>(dstI, cnt, E);
    scanA_k<<<NB, 256, 0, stream>>>(cnt, rowptr, bsum, N);
    scanB_k<<<1, 256, 0, stream>>>(bsum, NB);
    scanC_k<<<NB, 256, 0, stream>>>(rowptr, cursor, bsum, N, E);
    fill_k<<<EB4, 256, 0, stream>>>(srcI, dstI, cursor, colA, E);

    // layer 1
    agg_k<<<AB, 256, 0, stream>>>(x, rowptr, colA, aggbuf, N);
    mlp_k<true ><<<MB, 256, 0, stream>>>(aggbuf, x, Wl1, Wr1, bl1, h, N);
    // layer 2
    agg_k<<<AB, 256, 0, stream>>>(h, rowptr, colA, aggbuf, N);
    mlp_k<false><<<MB, 256, 0, stream>>>(aggbuf, h, Wl2, Wr2, bl2, out, N);
}